// Round 5
// baseline (467.074 us; speedup 1.0000x reference)
//
#include <hip/hip_runtime.h>
#include <math.h>

// ============================================================================
// ViT block on MI355X — Round 5:
//   * All-bf16 intermediates (h0, residuals h1b/h2b) — no fp32 round trips
//     except the final d_out write. Traffic ~2.2GB -> ~1.0GB.
//   * Swapped-operand MFMA (acc = mfma(W-frag, A-frag)): output layout
//     row=l15, cols=quad*4+reg -> vectorized 8B/16B epilogue stores and
//     vectorized residual loads.
//   * m97 global_load_lds staging; fast GELU; PE table.
// ============================================================================

#define M_TOK 32768

typedef __attribute__((ext_vector_type(8))) short  short8;   // 8 bf16 (4 VGPRs)
typedef __attribute__((ext_vector_type(4))) float  f32x4;
typedef __attribute__((ext_vector_type(8))) unsigned short us8v;
typedef __attribute__((ext_vector_type(4))) unsigned short us4v;

__device__ __forceinline__ unsigned short f2b(float f) {
    union { float f; unsigned u; } c; c.f = f;
    unsigned r = c.u + 0x7fffu + ((c.u >> 16) & 1u);   // RNE
    return (unsigned short)(r >> 16);
}
__device__ __forceinline__ float b2f(unsigned short u) {
    union { unsigned u; float f; } c; c.u = ((unsigned)u) << 16;
    return c.f;
}
__device__ __forceinline__ float gelu_fast(float x) {
    // 0.5x(1+tanh(c0(x+0.044715x^3))) == x * sigmoid(2*c0*(x+0.044715x^3))
    const float c0 = 0.7978845608028654f;            // sqrt(2/pi)
    const float c1 = 0.044715f * 0.7978845608028654f;
    float z = x * (c0 + c1 * x * x);
    float e = __expf(-2.0f * z);
    return x * __builtin_amdgcn_rcpf(1.0f + e);
}
// async global->LDS, 16B per lane; lds dest is wave-uniform base (+lane*16 by HW)
__device__ __forceinline__ void load_lds16(const unsigned short* g, void* lds) {
    __builtin_amdgcn_global_load_lds(
        (const __attribute__((address_space(1))) unsigned int*)g,
        (__attribute__((address_space(3))) unsigned int*)lds, 16, 0, 0);
}

// ---------------------------------------------------------------------------
// fp32 -> bf16 convert (n % 4 == 0)
// ---------------------------------------------------------------------------
__global__ __launch_bounds__(256) void cvt_f2b_kernel(
    const float* __restrict__ in, unsigned short* __restrict__ out, int n)
{
    int i = (blockIdx.x * 256 + threadIdx.x) * 4;
    if (i >= n) return;
    float4 v = *(const float4*)(in + i);
    us4v o;
    o[0] = f2b(v.x); o[1] = f2b(v.y); o[2] = f2b(v.z); o[3] = f2b(v.w);
    *(us4v*)(out + i) = o;
}

// ---------------------------------------------------------------------------
// Sinusoidal PE table: pe[pos][d], pos<1024, d<256.
// ---------------------------------------------------------------------------
__global__ __launch_bounds__(256) void pe_init_kernel(float* __restrict__ pe)
{
    const int pos = blockIdx.x;
    const int d   = threadIdx.x;
    const int ieven = d & ~1;
    float div = expf(-9.210340371976184f * (float)ieven * (1.0f / 256.0f));
    float ang = (float)pos * div;
    pe[pos * 256 + d] = (d & 1) ? cosf(ang) : sinf(ang);
}

// ---------------------------------------------------------------------------
// MFMA GEMM, swapped-operand layout: C = A (MxK) . W^T (NxK) + bias
// (+gelu) (+bf16 res). Output row = l15, cols = quad*4 + reg (4 consecutive).
// 128x128 tile, BK=32, 256 thr = 4 waves 2x2. LDS unpadded [128][32] bf16.
// res (if RES) is bf16 [M][N]; outF fp32; outB bf16.
// ---------------------------------------------------------------------------
template<bool GELU, bool RES, bool WF32, bool WB16>
__global__ __launch_bounds__(256) void mfma_gemm_kernel(
    const unsigned short* __restrict__ A, const unsigned short* __restrict__ W,
    const float* __restrict__ bias, const unsigned short* __restrict__ res,
    float* __restrict__ outF, unsigned short* __restrict__ outB,
    int M, int N, int K)
{
    __shared__ unsigned short As[128 * 32];
    __shared__ unsigned short Ws[128 * 32];

    const int t    = threadIdx.x;
    const int m0   = blockIdx.y * 128;
    const int n0   = blockIdx.x * 128;   // n-tile fast -> L2/L3 A-tile sharing
    const int wv   = t >> 6, lane = t & 63;
    const int wr   = (wv >> 1) * 64, wc = (wv & 1) * 64;
    const int l15  = lane & 15, quad = lane >> 4;

    f32x4 acc[4][4];
#pragma unroll
    for (int i = 0; i < 4; i++)
#pragma unroll
        for (int j = 0; j < 4; j++)
#pragma unroll
            for (int r = 0; r < 4; r++) acc[i][j][r] = 0.0f;

    // staging map: set s covers rows s*64 + wv*16 + (lane>>2), k-chunk (lane&3)*8
    const int srow = wv * 16 + (lane >> 2);
    const int skk  = (lane & 3) * 8;
    const unsigned short* gA0 = A + (size_t)(m0 + srow) * K + skk;
    const unsigned short* gA1 = gA0 + (size_t)64 * K;
    const unsigned short* gW0 = W + (size_t)(n0 + srow) * K + skk;
    const unsigned short* gW1 = gW0 + (size_t)64 * K;
    char* lA0 = (char*)As + wv * 1024;
    char* lA1 = lA0 + 4096;
    char* lW0 = (char*)Ws + wv * 1024;
    char* lW1 = lW0 + 4096;

    for (int k0 = 0; k0 < K; k0 += 32) {
        __syncthreads();                 // prior iter's ds_reads done
        load_lds16(gA0 + k0, lA0);
        load_lds16(gA1 + k0, lA1);
        load_lds16(gW0 + k0, lW0);
        load_lds16(gW1 + k0, lW1);
        __syncthreads();                 // drains vmcnt -> LDS visible

        short8 af[4], wf[4];
#pragma unroll
        for (int i = 0; i < 4; i++)
            af[i] = *(const short8*)&As[(wr + i * 16 + l15) * 32 + quad * 8];
#pragma unroll
        for (int j = 0; j < 4; j++)
            wf[j] = *(const short8*)&Ws[(wc + j * 16 + l15) * 32 + quad * 8];
        // swapped operands: D[n][m] -> lane holds row m=l15, cols n=quad*4+reg
#pragma unroll
        for (int i = 0; i < 4; i++)
#pragma unroll
            for (int j = 0; j < 4; j++)
                acc[i][j] = __builtin_amdgcn_mfma_f32_16x16x32_bf16(
                    wf[j], af[i], acc[i][j], 0, 0, 0);
    }

#pragma unroll
    for (int i = 0; i < 4; i++) {
        const int gr = m0 + wr + i * 16 + l15;
#pragma unroll
        for (int j = 0; j < 4; j++) {
            const int gc = n0 + wc + j * 16 + quad * 4;
            const float4 bv = *(const float4*)&bias[gc];
            float v0 = acc[i][j][0] + bv.x;
            float v1 = acc[i][j][1] + bv.y;
            float v2 = acc[i][j][2] + bv.z;
            float v3 = acc[i][j][3] + bv.w;
            if (GELU) {
                v0 = gelu_fast(v0); v1 = gelu_fast(v1);
                v2 = gelu_fast(v2); v3 = gelu_fast(v3);
            }
            if (RES) {
                us4v rv = *(const us4v*)&res[(size_t)gr * N + gc];
                v0 += b2f(rv[0]); v1 += b2f(rv[1]);
                v2 += b2f(rv[2]); v3 += b2f(rv[3]);
            }
            if (WF32) {
                float4 o; o.x = v0; o.y = v1; o.z = v2; o.w = v3;
                *(float4*)&outF[(size_t)gr * N + gc] = o;
            }
            if (WB16) {
                us4v o;
                o[0] = f2b(v0); o[1] = f2b(v1); o[2] = f2b(v2); o[3] = f2b(v3);
                *(us4v*)&outB[(size_t)gr * N + gc] = o;
            }
        }
    }
}

// ---------------------------------------------------------------------------
// Patch-embed MFMA GEMM: A gathered from bf16 image xb, W = conv_w bf16.
// Swapped-operand epilogue; writes bf16 h0.
// ---------------------------------------------------------------------------
__global__ __launch_bounds__(256) void patch_mfma_kernel(
    const unsigned short* __restrict__ xb, const unsigned short* __restrict__ W,
    const float* __restrict__ bias, unsigned short* __restrict__ outB)
{
    __shared__ unsigned short As[128 * 32];
    __shared__ unsigned short Ws[128 * 32];

    const int t    = threadIdx.x;
    const int m0   = blockIdx.y * 128;
    const int n0   = blockIdx.x * 128;
    const int wv   = t >> 6, lane = t & 63;
    const int wr   = (wv >> 1) * 64, wc = (wv & 1) * 64;
    const int l15  = lane & 15, quad = lane >> 4;

    f32x4 acc[4][4];
#pragma unroll
    for (int i = 0; i < 4; i++)
#pragma unroll
        for (int j = 0; j < 4; j++)
#pragma unroll
            for (int r = 0; r < 4; r++) acc[i][j][r] = 0.0f;

    const int srow = wv * 16 + (lane >> 2);
    const int skk  = (lane & 3) * 8;   // k-offset within BK: 0,8,16,24
    size_t xoff[2];
#pragma unroll
    for (int s = 0; s < 2; s++) {
        const int m  = m0 + s * 64 + srow;
        const int b  = m >> 10;
        const int idx = m & 1023;
        const int hh = idx >> 5, ww = idx & 31;
        xoff[s] = ((size_t)(b * 3) * 512 + (size_t)(hh * 16)) * 512 + ww * 16;
    }
    const unsigned short* gW0 = W + (size_t)(n0 + srow) * 768 + skk;
    const unsigned short* gW1 = gW0 + (size_t)64 * 768;
    char* lA0 = (char*)As + wv * 1024;
    char* lA1 = lA0 + 4096;
    char* lW0 = (char*)Ws + wv * 1024;
    char* lW1 = lW0 + 4096;

    for (int k0 = 0; k0 < 768; k0 += 32) {
        const int k  = k0 + skk;
        const int c  = k >> 8;
        const int ph = (k >> 4) & 15;
        const int pw = k & 15;          // 0 or 8
        const size_t koff = (size_t)c * 262144 + (size_t)ph * 512 + pw;
        __syncthreads();
        load_lds16(xb + xoff[0] + koff, lA0);
        load_lds16(xb + xoff[1] + koff, lA1);
        load_lds16(gW0 + k0, lW0);
        load_lds16(gW1 + k0, lW1);
        __syncthreads();

        short8 af[4], wf[4];
#pragma unroll
        for (int i = 0; i < 4; i++)
            af[i] = *(const short8*)&As[(wr + i * 16 + l15) * 32 + quad * 8];
#pragma unroll
        for (int j = 0; j < 4; j++)
            wf[j] = *(const short8*)&Ws[(wc + j * 16 + l15) * 32 + quad * 8];
#pragma unroll
        for (int i = 0; i < 4; i++)
#pragma unroll
            for (int j = 0; j < 4; j++)
                acc[i][j] = __builtin_amdgcn_mfma_f32_16x16x32_bf16(
                    wf[j], af[i], acc[i][j], 0, 0, 0);
    }

#pragma unroll
    for (int i = 0; i < 4; i++) {
        const int gr = m0 + wr + i * 16 + l15;
#pragma unroll
        for (int j = 0; j < 4; j++) {
            const int gc = n0 + wc + j * 16 + quad * 4;
            const float4 bv = *(const float4*)&bias[gc];
            us4v o;
            o[0] = f2b(acc[i][j][0] + bv.x);
            o[1] = f2b(acc[i][j][1] + bv.y);
            o[2] = f2b(acc[i][j][2] + bv.z);
            o[3] = f2b(acc[i][j][3] + bv.w);
            *(us4v*)&outB[(size_t)gr * 256 + gc] = o;
        }
    }
}

// ---------------------------------------------------------------------------
// LayerNorm + PE (table). One block = one token; bf16 in, bf16 out.
// ---------------------------------------------------------------------------
__global__ __launch_bounds__(256) void ln_pe_kernel(
    const unsigned short* __restrict__ in, const float* __restrict__ w,
    const float* __restrict__ b, const float* __restrict__ pe_t,
    unsigned short* __restrict__ outB)
{
    const int m = blockIdx.x;
    const int d = threadIdx.x;
    float v = b2f(in[(size_t)m * 256 + d]);

    float s = v, s2 = v * v;
#pragma unroll
    for (int off = 32; off > 0; off >>= 1) {
        s  += __shfl_down(s,  off, 64);
        s2 += __shfl_down(s2, off, 64);
    }
    __shared__ float ss[4], ss2[4], stats[2];
    const int lane = d & 63, wid = d >> 6;
    if (lane == 0) { ss[wid] = s; ss2[wid] = s2; }
    __syncthreads();
    if (d == 0) {
        float a  = ss[0] + ss[1] + ss[2] + ss[3];
        float a2 = ss2[0] + ss2[1] + ss2[2] + ss2[3];
        float mean = a * (1.0f / 256.0f);
        float var  = a2 * (1.0f / 256.0f) - mean * mean;
        stats[0] = mean;
        stats[1] = rsqrtf(var + 1e-5f);
    }
    __syncthreads();
    const float mean = stats[0], rstd = stats[1];

    const int pos = m & 1023;
    float pe = pe_t[pos * 256 + d];

    float o = (v - mean) * rstd * w[d] + b[d] + pe;
    outB[(size_t)m * 256 + d] = f2b(o);
}

// ---------------------------------------------------------------------------
// MFMA windowed attention. One block = one (batch, window, head).
// ---------------------------------------------------------------------------
__global__ __launch_bounds__(256) void attn_mfma_kernel(
    const unsigned short* __restrict__ qkv, unsigned short* __restrict__ out)
{
    __shared__ unsigned short Ps[64 * 72];   // P, stride 72 (b128-aligned, padded)
    __shared__ unsigned short Vt[32 * 72];   // V^T [headdim][key]

    const int blk = blockIdx.x;        // 0..4095
    const int h = blk & 7;
    const int w = (blk >> 3) & 15;
    const int b = blk >> 7;
    const int m_base = b * 1024 + w * 64;

    const int t = threadIdx.x;
    const int wv = t >> 6, lane = t & 63;
    const int l15 = lane & 15, quad = lane >> 4;

    // ---- stage V^T (cooperative, 8 elems/thread) ----
    {
        const int row = t >> 2;             // key 0..63
        const int c0  = (t & 3) * 8;        // headdim chunk
        const unsigned short* src = qkv + (size_t)(m_base + row) * 768 + 512 + h * 32 + c0;
        us8v v = *(const us8v*)src;
#pragma unroll
        for (int j = 0; j < 8; j++) Vt[(c0 + j) * 72 + row] = v[j];
    }

    // ---- QK^T: S strip (16x64) = 4 MFMAs ----
    short8 aq = *(const short8*)(qkv + (size_t)(m_base + wv * 16 + l15) * 768 + h * 32 + quad * 8);
    f32x4 c[4];
#pragma unroll
    for (int j = 0; j < 4; j++) {
        short8 bk = *(const short8*)(qkv + (size_t)(m_base + j * 16 + l15) * 768 + 256 + h * 32 + quad * 8);
        f32x4 z = {0.0f, 0.0f, 0.0f, 0.0f};
        c[j] = __builtin_amdgcn_mfma_f32_16x16x32_bf16(aq, bk, z, 0, 0, 0);
    }

    // ---- softmax over keys (row = quad*4+reg, col = j*16+l15) ----
    const float scale = 0.17677669529663687f; // 1/sqrt(32)
    float sm[4];
#pragma unroll
    for (int r = 0; r < 4; r++) {
        float m0 = -1e30f;
#pragma unroll
        for (int j = 0; j < 4; j++) { c[j][r] *= scale; m0 = fmaxf(m0, c[j][r]); }
#pragma unroll
        for (int d = 1; d < 16; d <<= 1) m0 = fmaxf(m0, __shfl_xor(m0, d, 64));
        float s0 = 0.0f;
#pragma unroll
        for (int j = 0; j < 4; j++) { float e = __expf(c[j][r] - m0); c[j][r] = e; s0 += e; }
#pragma unroll
        for (int d = 1; d < 16; d <<= 1) s0 += __shfl_xor(s0, d, 64);
        sm[r] = __builtin_amdgcn_rcpf(s0);
    }

    // ---- write P (bf16) to LDS ----
#pragma unroll
    for (int r = 0; r < 4; r++) {
        const int prow = wv * 16 + quad * 4 + r;
#pragma unroll
        for (int j = 0; j < 4; j++)
            Ps[prow * 72 + j * 16 + l15] = f2b(c[j][r] * sm[r]);
    }
    __syncthreads();

    // ---- PV: O strip (16x32) = 4 MFMAs ----
    short8 ap0 = *(const short8*)&Ps[(wv * 16 + l15) * 72 + quad * 8];
    short8 ap1 = *(const short8*)&Ps[(wv * 16 + l15) * 72 + 32 + quad * 8];
    f32x4 o[2];
#pragma unroll
    for (int nt = 0; nt < 2; nt++) {
        short8 bv0 = *(const short8*)&Vt[(nt * 16 + l15) * 72 + quad * 8];
        short8 bv1 = *(const short8*)&Vt[(nt * 16 + l15) * 72 + 32 + quad * 8];
        f32x4 z = {0.0f, 0.0f, 0.0f, 0.0f};
        o[nt] = __builtin_amdgcn_mfma_f32_16x16x32_bf16(ap0, bv0, z, 0, 0, 0);
        o[nt] = __builtin_amdgcn_mfma_f32_16x16x32_bf16(ap1, bv1, o[nt], 0, 0, 0);
    }

    // ---- write O (bf16) ----
#pragma unroll
    for (int nt = 0; nt < 2; nt++) {
#pragma unroll
        for (int r = 0; r < 4; r++) {
            const int row = m_base + wv * 16 + quad * 4 + r;
            out[(size_t)row * 256 + h * 32 + nt * 16 + l15] = f2b(o[nt][r]);
        }
    }
}

// ---------------------------------------------------------------------------
// Workspace layout (bytes), total ~187.3 MB:
//   SLOT_A @ 0          (67.1M): xb (K0..K1) -> hidden bf16 (K3..K4, K8..K9)
//   SLOT_B @ 67108864   (50.3M): h0b bf16 (K1..K2) -> qkvb bf16 (K5..K6)
//   pe_t   @ 117440512  (1.0M):  fp32 PE table (K0..K2)
//   h1b    @ 118489088  (16.8M): LN+PE out, residual (K2..K7)
//   f1b    @ 135266304  (16.8M): ffn1 out (K4..K5)
//   h2b    @ 152043520  (16.8M): h2 = proj+res (K7..K9)
//   aob    @ 168820736  (16.8M): attn out (K6..K7)
//   wts    @ 185597952  (~1.6M): bf16 conv_w, qkv_w, proj_w, ff_w1, ff_w2
// ---------------------------------------------------------------------------
extern "C" void kernel_launch(void* const* d_in, const int* in_sizes, int n_in,
                              void* d_out, int out_size, void* d_ws, size_t ws_size,
                              hipStream_t stream)
{
    const float* x      = (const float*)d_in[0];
    const float* conv_w = (const float*)d_in[1];
    const float* conv_b = (const float*)d_in[2];
    const float* ln_w   = (const float*)d_in[3];
    const float* ln_b   = (const float*)d_in[4];
    const float* qkv_w  = (const float*)d_in[5];
    const float* qkv_b  = (const float*)d_in[6];
    const float* proj_w = (const float*)d_in[7];
    const float* proj_b = (const float*)d_in[8];
    const float* ff_w1  = (const float*)d_in[9];
    const float* ff_b1  = (const float*)d_in[10];
    const float* ff_w2  = (const float*)d_in[11];
    const float* ff_b2  = (const float*)d_in[12];
    float* out = (float*)d_out;

    char* ws = (char*)d_ws;
    unsigned short* xb    = (unsigned short*)(ws);                 // SLOT_A
    unsigned short* hidb  = (unsigned short*)(ws);                 // SLOT_A reuse
    unsigned short* h0b   = (unsigned short*)(ws + 67108864);      // SLOT_B
    unsigned short* qkvb  = (unsigned short*)(ws + 67108864);      // SLOT_B reuse
    float*          pe_t  = (float*)(ws + 117440512);
    unsigned short* h1b   = (unsigned short*)(ws + 118489088);
    unsigned short* f1b   = (unsigned short*)(ws + 135266304);
    unsigned short* h2b   = (unsigned short*)(ws + 152043520);
    unsigned short* aob   = (unsigned short*)(ws + 168820736);
    unsigned short* wbase = (unsigned short*)(ws + 185597952);
    unsigned short* conv_wb = wbase;                 // 196608
    unsigned short* qkv_wb  = wbase + 196608;        // 196608
    unsigned short* proj_wb = wbase + 393216;        // 65536
    unsigned short* ff_w1b  = wbase + 458752;        // 262144
    unsigned short* ff_w2b  = wbase + 720896;        // 262144

    const int M = M_TOK;
    dim3 blk(256);

    // K0: conversions + PE table
    cvt_f2b_kernel<<<dim3(25165824 / 1024), blk, 0, stream>>>(x, xb, 25165824);
    cvt_f2b_kernel<<<dim3(196608 / 1024), blk, 0, stream>>>(conv_w, conv_wb, 196608);
    cvt_f2b_kernel<<<dim3(196608 / 1024), blk, 0, stream>>>(qkv_w, qkv_wb, 196608);
    cvt_f2b_kernel<<<dim3(65536 / 1024), blk, 0, stream>>>(proj_w, proj_wb, 65536);
    cvt_f2b_kernel<<<dim3(262144 / 1024), blk, 0, stream>>>(ff_w1, ff_w1b, 262144);
    cvt_f2b_kernel<<<dim3(262144 / 1024), blk, 0, stream>>>(ff_w2, ff_w2b, 262144);
    pe_init_kernel<<<dim3(1024), blk, 0, stream>>>(pe_t);

    // K1: patch embed -> h0b (bf16)
    patch_mfma_kernel<<<dim3(2, M / 128), blk, 0, stream>>>(xb, conv_wb, conv_b, h0b);
    // K2: LN + PE -> h1b (bf16; also the attn-block residual)
    ln_pe_kernel<<<dim3(M), blk, 0, stream>>>(h0b, ln_w, ln_b, pe_t, h1b);
    // K3: FFN1a: gelu(h1 @ w1^T + b1) -> hidb
    mfma_gemm_kernel<true, false, false, true><<<dim3(8, M / 128), blk, 0, stream>>>(
        h1b, ff_w1b, ff_b1, nullptr, nullptr, hidb, M, 1024, 256);
    // K4: FFN1b: hidb @ w2^T + b2 -> f1b
    mfma_gemm_kernel<false, false, false, true><<<dim3(2, M / 128), blk, 0, stream>>>(
        hidb, ff_w2b, ff_b2, nullptr, nullptr, f1b, M, 256, 1024);
    // K5: qkv: f1b @ qkv_w^T + qkv_b -> qkvb
    mfma_gemm_kernel<false, false, false, true><<<dim3(6, M / 128), blk, 0, stream>>>(
        f1b, qkv_wb, qkv_b, nullptr, nullptr, qkvb, M, 768, 256);
    // K6: windowed attention (MFMA): qkvb -> aob
    attn_mfma_kernel<<<dim3(4096), blk, 0, stream>>>(qkvb, aob);
    // K7: h2 = aob @ proj_w^T + proj_b + h1b -> h2b (bf16 only)
    mfma_gemm_kernel<false, true, false, true><<<dim3(2, M / 128), blk, 0, stream>>>(
        aob, proj_wb, proj_b, h1b, nullptr, h2b, M, 256, 256);
    // K8: FFN2a: gelu(h2b @ w1^T + b1) -> hidb
    mfma_gemm_kernel<true, false, false, true><<<dim3(8, M / 128), blk, 0, stream>>>(
        h2b, ff_w1b, ff_b1, nullptr, nullptr, hidb, M, 1024, 256);
    // K9: FFN2b + final residual: hidb @ w2^T + b2 + h2b -> out (fp32)
    mfma_gemm_kernel<false, true, true, false><<<dim3(2, M / 128), blk, 0, stream>>>(
        hidb, ff_w2b, ff_b2, h2b, out, nullptr, M, 256, 1024);
}